// Round 6
// baseline (155.450 us; speedup 1.0000x reference)
//
#include <hip/hip_runtime.h>
#include <math.h>

// Causal flash attention, B=2 H=16 S=2048 D=64, fp32 in/out, bf16 MFMA compute.
// R11: zero-sync + coalesced frag buffers (R10) with (a) inline-asm load
// pipeline: global_load_dwordx4 issued 1 unit ahead, counted s_waitcnt
// vmcnt(8) + sched_barrier(0) before consume (compiler cannot break it;
// R10's VGPR=92 proved it sank the prefetch), and (b) UNIFORM waves: each
// wave owns q-set pair (s, 63-s) = exactly 65 units; shared k<=s range loads
// kf/vf once for both sets (ILP + traffic cut). 1024 waves / 256 blocks,
// 1 block/CU, XCD-bijective map = 4 bh per XCD (3 MB frag set < 4 MB L2).
// l via ones-MFMA. Wave-local epilogue writes final fp32 O. No combine.
// Carried: Q pre-scaled bf16 prepass, P pack via v_perm, permlane32_swap
// P-exchange, persistent zero-C, setprio(1) on MFMA clusters.

constexpr int kS   = 2048;
constexpr int kD   = 64;
constexpr int kBH  = 32;
constexpr int kPadP = 72;           // prep-kernel LDS pad only
constexpr int kFragBH = 64 * 4 * 512;   // u16 per bh: 64 units x 4 chunks x 512

typedef short short8 __attribute__((ext_vector_type(8)));
typedef float float4v __attribute__((ext_vector_type(4)));
typedef float float16v __attribute__((ext_vector_type(16)));
typedef unsigned int u32;
typedef unsigned int u32x4 __attribute__((ext_vector_type(4)));
typedef unsigned short u16;

static __device__ inline u16 f2bf(float f) {
  union { float f; unsigned u; } v; v.f = f;
  unsigned r = v.u + 0x7FFF + ((v.u >> 16) & 1);   // RNE
  return (u16)(r >> 16);
}

static __device__ inline short8 pack8(float4v a, float4v b) {
  short8 r;
  r[0] = (short)f2bf(a[0]); r[1] = (short)f2bf(a[1]);
  r[2] = (short)f2bf(a[2]); r[3] = (short)f2bf(a[3]);
  r[4] = (short)f2bf(b[0]); r[5] = (short)f2bf(b[1]);
  r[6] = (short)f2bf(b[2]); r[7] = (short)f2bf(b[3]);
  return r;
}

// half-swap: v_permlane32_swap_b32 A, B : A.hi-lanes <-> B.lo-lanes
static __device__ inline void swap32(u32 a, u32 b, u32& oa, u32& ob) {
#if __has_builtin(__builtin_amdgcn_permlane32_swap)
  auto r = __builtin_amdgcn_permlane32_swap(a, b, false, false);
  oa = r[0]; ob = r[1];
#else
  asm volatile("v_permlane32_swap_b32 %0, %1" : "+v"(a), "+v"(b));
  oa = a; ob = b;
#endif
}

// raw asm 16B load: forces issue point + keeps dest regs live (pipeline
// cannot be sunk by the scheduler; volatile asm keeps program order vs the
// volatile waitcnt below).
static __device__ inline void gload16(u32x4& d, const u16* p) {
  asm volatile("global_load_dwordx4 %0, %1, off" : "=v"(d) : "v"(p));
}
static __device__ inline short8 asfrag(u32x4 u) {
  union { u32x4 u; short8 s; } c; c.u = u; return c.s;
}

// ---- prepass: write fragment-order buffers ----
// Qf/Kf chunk(set/unit u, dk, lane): elem = X[row u*32 + (lane&31)][dk*16 + (lane>>5)*8 .. +8]
// Vf  chunk(unit u, c, lane): elem = V^T[d = (c&1)*32 + (lane&31)][key u*32 + (c>>1)*16 + (lane>>5)*8 .. +8]
__global__ __launch_bounds__(256)
void prep_kernel(const float* __restrict__ Q, const float* __restrict__ K,
                 const float* __restrict__ V,
                 u16* __restrict__ Qf, u16* __restrict__ Kf, u16* __restrict__ Vf) {
  __shared__ u16 tile[64 * kPadP];
  const int tid = threadIdx.x;
  const int bh = blockIdx.y, st = blockIdx.x;
  const size_t ibase = (size_t)bh * kS * kD + (size_t)st * 64 * kD;
  const size_t fbase = (size_t)bh * kFragBH;
  const int r  = tid >> 2;        // row within 64-row tile
  const int c0 = (tid & 3) * 16;  // col start
  const int dk = tid & 3;
  const int U  = st * 2 + (r >> 5);   // global 32-row unit/set index
  const int lr = r & 31;
  {
    const float scl = 0.125f * 1.44269504089f;   // 1/sqrt(64) * log2(e)
    const float* qp = Q + ibase + (size_t)r * kD + c0;
    float4v a = *(const float4v*)(qp);
    float4v b = *(const float4v*)(qp + 4);
    float4v c = *(const float4v*)(qp + 8);
    float4v d = *(const float4v*)(qp + 12);
    #pragma unroll
    for (int i = 0; i < 4; ++i) { a[i] *= scl; b[i] *= scl; c[i] *= scl; d[i] *= scl; }
    u16* dst = Qf + fbase + (size_t)(U * 4 + dk) * 512;
    *(short8*)(dst + lr * 8)        = pack8(a, b);   // h=0 chunk
    *(short8*)(dst + (32 + lr) * 8) = pack8(c, d);   // h=1 chunk
  }
  {
    const float* kp = K + ibase + (size_t)r * kD + c0;
    float4v a = *(const float4v*)(kp);
    float4v b = *(const float4v*)(kp + 4);
    float4v c = *(const float4v*)(kp + 8);
    float4v d = *(const float4v*)(kp + 12);
    u16* dst = Kf + fbase + (size_t)(U * 4 + dk) * 512;
    *(short8*)(dst + lr * 8)        = pack8(a, b);
    *(short8*)(dst + (32 + lr) * 8) = pack8(c, d);
  }
  {
    const float* vp = V + ibase + (size_t)r * kD + c0;
    float4v a = *(const float4v*)(vp);
    float4v b = *(const float4v*)(vp + 4);
    float4v c = *(const float4v*)(vp + 8);
    float4v d = *(const float4v*)(vp + 12);
    u16* t = &tile[r * kPadP + c0];
    *(short8*)t       = pack8(a, b);
    *(short8*)(t + 8) = pack8(c, d);
  }
  __syncthreads();
  {
    const int dd = tid >> 2;          // d-row of V^T
    const int s0 = (tid & 3) * 16;    // key col start within tile
    short8 w0, w1;
    #pragma unroll
    for (int i = 0; i < 8; ++i) {
      w0[i] = (short)tile[(s0 + i) * kPadP + dd];
      w1[i] = (short)tile[(s0 + 8 + i) * kPadP + dd];
    }
    const int ku   = st * 2 + (s0 >> 5);        // unit index
    const int koff = s0 & 31;                   // 0 or 16
    const int c    = ((koff >> 4) << 1) | (dd >> 5);
    u16* vdst = Vf + fbase + (size_t)(ku * 4 + c) * 512;
    *(short8*)(vdst + (dd & 31) * 8)        = w0;   // h=0 (key +0..7)
    *(short8*)(vdst + (32 + (dd & 31)) * 8) = w1;   // h=1 (key +8..15)
  }
}

// ---- main flash kernel: zero-sync, asm-pipelined frag loads, final O ----
__global__ __launch_bounds__(256, 1)
void fattn_kernel(const u16* __restrict__ Qf, const u16* __restrict__ Kf,
                  const u16* __restrict__ Vf, float* __restrict__ O) {
  const int tid  = threadIdx.x;
  const int wave = tid >> 6;
  const int lane = tid & 63;
  const int l31  = lane & 31;
  const int h    = lane >> 5;

  // XCD-bijective map: xcd = blockIdx&7 hosts bh in {4*xcd .. 4*xcd+3}
  const int b   = blockIdx.x;
  const int m   = b >> 3;
  const int bh  = (b & 7) * 4 + (m & 3);
  const int sg  = m >> 2;             // 0..7
  const int sA  = sg * 4 + wave;      // 0..31  (small set)
  const int sB  = 63 - sA;            // 32..63 (large set)
  const int q0A = sA * 32, q0B = sB * 32;
  const int kend = sB;                // loop 0..kend, 65 units total per wave

  const size_t fb = (size_t)bh * kFragBH;
  const u16* gk = Kf + fb + lane * 8;   // + u*2048 + dk*512
  const u16* gv = Vf + fb + lane * 8;   // + u*2048 + c*512

  float16v zf;
  #pragma unroll
  for (int i = 0; i < 16; ++i) zf[i] = 0.f;

  short8 ones;
  #pragma unroll
  for (int i = 0; i < 8; ++i) ones[i] = (short)0x3F80;

  // Q fragments for both sets (compiler loads; drained by prologue vmcnt(0))
  short8 qfA[4], qfB[4];
  {
    const u16* qa = Qf + fb + (size_t)(sA * 4) * 512 + lane * 8;
    const u16* qb = Qf + fb + (size_t)(sB * 4) * 512 + lane * 8;
    #pragma unroll
    for (int dk = 0; dk < 4; ++dk) {
      qfA[dk] = *(const short8*)(qa + dk * 512);
      qfB[dk] = *(const short8*)(qb + dk * 512);
    }
  }

  float16v a0A = zf, a1A = zf, laA = zf;
  float16v a0B = zf, a1B = zf, laB = zf;
  const int qgA = q0A + l31, qgB = q0B + l31;

  u32x4 kX[4], vX[4], kY[4], vY[4];   // double-buffered fragments

  // prologue: issue unit 0, drain everything (Q + unit0)
  #pragma unroll
  for (int i = 0; i < 4; ++i) gload16(kX[i], gk + i * 512);
  #pragma unroll
  for (int i = 0; i < 4; ++i) gload16(vX[i], gv + i * 512);
  asm volatile("s_waitcnt vmcnt(0)" ::: "memory");
  __builtin_amdgcn_sched_barrier(0);

  // per-set compute for one 32x32 unit
  auto doSet = [&](const short8* qf, float16v& a0, float16v& a1, float16v& la,
                   int qg, int sdiag, int k, const u32x4* kc, const u32x4* vc) {
    __builtin_amdgcn_s_setprio(1);
    float16v sv = __builtin_amdgcn_mfma_f32_32x32x16_bf16(asfrag(kc[0]), qf[0], zf, 0, 0, 0);
    sv = __builtin_amdgcn_mfma_f32_32x32x16_bf16(asfrag(kc[1]), qf[1], sv, 0, 0, 0);
    sv = __builtin_amdgcn_mfma_f32_32x32x16_bf16(asfrag(kc[2]), qf[2], sv, 0, 0, 0);
    sv = __builtin_amdgcn_mfma_f32_32x32x16_bf16(asfrag(kc[3]), qf[3], sv, 0, 0, 0);
    __builtin_amdgcn_s_setprio(0);

    if (k == sdiag) {   // diagonal subtile
      #pragma unroll
      for (int r = 0; r < 16; ++r) {
        const int kg = k * 32 + (r & 3) + 8 * (r >> 2) + 4 * h;
        if (kg > qg) sv[r] = -1e30f;
      }
    }

    u32 pk[8];
    #pragma unroll
    for (int g2 = 0; g2 < 4; ++g2) {
      const u32 u0 = __float_as_uint(__builtin_amdgcn_exp2f(sv[4 * g2 + 0]));
      const u32 u1 = __float_as_uint(__builtin_amdgcn_exp2f(sv[4 * g2 + 1]));
      const u32 u2 = __float_as_uint(__builtin_amdgcn_exp2f(sv[4 * g2 + 2]));
      const u32 u3 = __float_as_uint(__builtin_amdgcn_exp2f(sv[4 * g2 + 3]));
      pk[2 * g2]     = __builtin_amdgcn_perm(u1, u0, 0x07060302u);
      pk[2 * g2 + 1] = __builtin_amdgcn_perm(u3, u2, 0x07060302u);
    }

    {
      union { u32 u[4]; short8 s8; } pf;
      swap32(pk[0], pk[2], pf.u[0], pf.u[2]);
      swap32(pk[1], pk[3], pf.u[1], pf.u[3]);
      __builtin_amdgcn_s_setprio(1);
      a0 = __builtin_amdgcn_mfma_f32_32x32x16_bf16(pf.s8, asfrag(vc[0]), a0, 0, 0, 0);
      a1 = __builtin_amdgcn_mfma_f32_32x32x16_bf16(pf.s8, asfrag(vc[1]), a1, 0, 0, 0);
      la = __builtin_amdgcn_mfma_f32_32x32x16_bf16(pf.s8, ones,          la, 0, 0, 0);
      __builtin_amdgcn_s_setprio(0);
    }
    {
      union { u32 u[4]; short8 s8; } pf;
      swap32(pk[4], pk[6], pf.u[0], pf.u[2]);
      swap32(pk[5], pk[7], pf.u[1], pf.u[3]);
      __builtin_amdgcn_s_setprio(1);
      a0 = __builtin_amdgcn_mfma_f32_32x32x16_bf16(pf.s8, asfrag(vc[2]), a0, 0, 0, 0);
      a1 = __builtin_amdgcn_mfma_f32_32x32x16_bf16(pf.s8, asfrag(vc[3]), a1, 0, 0, 0);
      la = __builtin_amdgcn_mfma_f32_32x32x16_bf16(pf.s8, ones,          la, 0, 0, 0);
      __builtin_amdgcn_s_setprio(0);
    }
  };

  // one unit: prefetch k+1 into (kn,vn), counted wait, consume (kc,vc)
  auto unit = [&](const u32x4* kc, const u32x4* vc, u32x4* kn, u32x4* vn, int k) {
    if (k < kend) {
      const u16* pk_ = gk + (size_t)(k + 1) * 2048;
      const u16* pv_ = gv + (size_t)(k + 1) * 2048;
      #pragma unroll
      for (int i = 0; i < 4; ++i) gload16(kn[i], pk_ + i * 512);
      #pragma unroll
      for (int i = 0; i < 4; ++i) gload16(vn[i], pv_ + i * 512);
      asm volatile("s_waitcnt vmcnt(8)" ::: "memory");   // current unit ready
    } else {
      asm volatile("s_waitcnt vmcnt(0)" ::: "memory");
    }
    __builtin_amdgcn_sched_barrier(0);

    doSet(qfB, a0B, a1B, laB, qgB, sB, k, kc, vc);       // large set: always
    if (k <= sA)
      doSet(qfA, a0A, a1A, laA, qgA, sA, k, kc, vc);     // small set: shared range
  };

  int k = 0;
  for (;;) {
    unit(kX, vX, kY, vY, k);
    if (++k > kend) break;
    unit(kY, vY, kX, vX, k);
    if (++k > kend) break;
  }

  // ---- wave-local epilogue: O = acc / l, final fp32, both sets ----
  #pragma unroll
  for (int r = 0; r < 16; ++r) {
    const int row = (r & 3) + 8 * (r >> 2) + 4 * h;
    const float invA = 1.f / laA[r];
    const float invB = 1.f / laB[r];
    float* opA = O + ((size_t)bh * kS + q0A + row) * kD;
    float* opB = O + ((size_t)bh * kS + q0B + row) * kD;
    opA[l31]      = a0A[r] * invA;
    opA[l31 + 32] = a1A[r] * invA;
    opB[l31]      = a0B[r] * invB;
    opB[l31 + 32] = a1B[r] * invB;
  }
}

extern "C" void kernel_launch(void* const* d_in, const int* in_sizes, int n_in,
                              void* d_out, int out_size, void* d_ws, size_t ws_size,
                              hipStream_t stream) {
  const float* Q = (const float*)d_in[0];
  const float* K = (const float*)d_in[1];
  const float* V = (const float*)d_in[2];
  float* O = (float*)d_out;

  const size_t nKV = (size_t)kBH * kS * kD;      // 4.19M elems
  u16* Qf = (u16*)d_ws;                          // 8.39 MB
  u16* Kf = Qf + nKV;                            // 8.39 MB
  u16* Vf = Kf + nKV;                            // 8.39 MB

  dim3 gprep(kS / 64, kBH);
  prep_kernel<<<gprep, 256, 0, stream>>>(Q, K, V, Qf, Kf, Vf);
  fattn_kernel<<<256, 256, 0, stream>>>(Qf, Kf, Vf, O);
}

// Round 7
// 135.993 us; speedup vs baseline: 1.1431x; 1.1431x over previous
//
#include <hip/hip_runtime.h>
#include <math.h>

// Causal flash attention, B=2 H=16 S=2048 D=64, fp32 in/out, bf16 MFMA compute.
// R12: max-TLP zero-sync. Lesson R7..R11: fattn time tracks resident
// waves/CU (R11 ILP pipeline at 1 wave/SIMD LOST to TLP). So: 4096 uniform
// waves (block = pair (sA,63-sA), its 65 units chunked 4 ways contiguously
// over [B-range|A-range] -> every wave 16-17 units, zero tail), lean VGPR
// (single-buffered compiler loads, VALU l-sum, ONE live acc set per wave;
// transition wave dumps its first partial mid-loop), launch_bounds(256,3)
// -> target 12 waves/CU = 3/SIMD (1.5x R7's best). Coalesced frag buffers
// (R10: FETCH 12MB, conflicts 0) kept. In-block combine: 5 bf16-packed LDS
// slots (21.8KB), ONE __syncthreads, final fp32 O direct. No combine kernel.
// Carried: Q pre-scaled bf16 prepass, P pack via v_perm, permlane32_swap
// P-exchange, persistent zero-C, setprio(1) on MFMA clusters.

constexpr int kS   = 2048;
constexpr int kD   = 64;
constexpr int kBH  = 32;
constexpr int kPadP = 72;           // prep-kernel LDS pad only
constexpr int kFragBH = 64 * 4 * 512;   // u16 per bh: 64 units x 4 chunks x 512

typedef short short8 __attribute__((ext_vector_type(8)));
typedef float float4v __attribute__((ext_vector_type(4)));
typedef float float16v __attribute__((ext_vector_type(16)));
typedef unsigned int u32;
typedef unsigned short u16;

static __device__ inline u16 f2bf(float f) {
  union { float f; unsigned u; } v; v.f = f;
  unsigned r = v.u + 0x7FFF + ((v.u >> 16) & 1);   // RNE
  return (u16)(r >> 16);
}

static __device__ inline short8 pack8(float4v a, float4v b) {
  short8 r;
  r[0] = (short)f2bf(a[0]); r[1] = (short)f2bf(a[1]);
  r[2] = (short)f2bf(a[2]); r[3] = (short)f2bf(a[3]);
  r[4] = (short)f2bf(b[0]); r[5] = (short)f2bf(b[1]);
  r[6] = (short)f2bf(b[2]); r[7] = (short)f2bf(b[3]);
  return r;
}

// half-swap: v_permlane32_swap_b32 A, B : A.hi-lanes <-> B.lo-lanes
static __device__ inline void swap32(u32 a, u32 b, u32& oa, u32& ob) {
#if __has_builtin(__builtin_amdgcn_permlane32_swap)
  auto r = __builtin_amdgcn_permlane32_swap(a, b, false, false);
  oa = r[0]; ob = r[1];
#else
  asm volatile("v_permlane32_swap_b32 %0, %1" : "+v"(a), "+v"(b));
  oa = a; ob = b;
#endif
}

// ---- prepass: write fragment-order buffers ----
// Qf/Kf chunk(set/unit u, dk, lane): elem = X[row u*32 + (lane&31)][dk*16 + (lane>>5)*8 .. +8]
// Vf  chunk(unit u, c, lane): elem = V^T[d = (c&1)*32 + (lane&31)][key u*32 + (c>>1)*16 + (lane>>5)*8 .. +8]
__global__ __launch_bounds__(256)
void prep_kernel(const float* __restrict__ Q, const float* __restrict__ K,
                 const float* __restrict__ V,
                 u16* __restrict__ Qf, u16* __restrict__ Kf, u16* __restrict__ Vf) {
  __shared__ u16 tile[64 * kPadP];
  const int tid = threadIdx.x;
  const int bh = blockIdx.y, st = blockIdx.x;
  const size_t ibase = (size_t)bh * kS * kD + (size_t)st * 64 * kD;
  const size_t fbase = (size_t)bh * kFragBH;
  const int r  = tid >> 2;        // row within 64-row tile
  const int c0 = (tid & 3) * 16;  // col start
  const int dk = tid & 3;
  const int U  = st * 2 + (r >> 5);   // global 32-row unit/set index
  const int lr = r & 31;
  {
    const float scl = 0.125f * 1.44269504089f;   // 1/sqrt(64) * log2(e)
    const float* qp = Q + ibase + (size_t)r * kD + c0;
    float4v a = *(const float4v*)(qp);
    float4v b = *(const float4v*)(qp + 4);
    float4v c = *(const float4v*)(qp + 8);
    float4v d = *(const float4v*)(qp + 12);
    #pragma unroll
    for (int i = 0; i < 4; ++i) { a[i] *= scl; b[i] *= scl; c[i] *= scl; d[i] *= scl; }
    u16* dst = Qf + fbase + (size_t)(U * 4 + dk) * 512;
    *(short8*)(dst + lr * 8)        = pack8(a, b);   // h=0 chunk
    *(short8*)(dst + (32 + lr) * 8) = pack8(c, d);   // h=1 chunk
  }
  {
    const float* kp = K + ibase + (size_t)r * kD + c0;
    float4v a = *(const float4v*)(kp);
    float4v b = *(const float4v*)(kp + 4);
    float4v c = *(const float4v*)(kp + 8);
    float4v d = *(const float4v*)(kp + 12);
    u16* dst = Kf + fbase + (size_t)(U * 4 + dk) * 512;
    *(short8*)(dst + lr * 8)        = pack8(a, b);
    *(short8*)(dst + (32 + lr) * 8) = pack8(c, d);
  }
  {
    const float* vp = V + ibase + (size_t)r * kD + c0;
    float4v a = *(const float4v*)(vp);
    float4v b = *(const float4v*)(vp + 4);
    float4v c = *(const float4v*)(vp + 8);
    float4v d = *(const float4v*)(vp + 12);
    u16* t = &tile[r * kPadP + c0];
    *(short8*)t       = pack8(a, b);
    *(short8*)(t + 8) = pack8(c, d);
  }
  __syncthreads();
  {
    const int dd = tid >> 2;          // d-row of V^T
    const int s0 = (tid & 3) * 16;    // key col start within tile
    short8 w0, w1;
    #pragma unroll
    for (int i = 0; i < 8; ++i) {
      w0[i] = (short)tile[(s0 + i) * kPadP + dd];
      w1[i] = (short)tile[(s0 + 8 + i) * kPadP + dd];
    }
    const int ku   = st * 2 + (s0 >> 5);        // unit index
    const int koff = s0 & 31;                   // 0 or 16
    const int c    = ((koff >> 4) << 1) | (dd >> 5);
    u16* vdst = Vf + fbase + (size_t)(ku * 4 + c) * 512;
    *(short8*)(vdst + (dd & 31) * 8)        = w0;   // h=0 (key +0..7)
    *(short8*)(vdst + (32 + (dd & 31)) * 8) = w1;   // h=1 (key +8..15)
  }
}

// ---- main flash kernel: zero-sync loop, in-block combine, final O ----
__global__ __launch_bounds__(256, 3)
void fattn_kernel(const u16* __restrict__ Qf, const u16* __restrict__ Kf,
                  const u16* __restrict__ Vf, float* __restrict__ O) {
  __shared__ u32   ldsP[5][32][33];   // bf16-pair packed partials (padded)
  __shared__ float ldsL[5][32];

  const int tid  = threadIdx.x;
  const int wave = tid >> 6;
  const int lane = tid & 63;
  const int l31  = lane & 31;
  const int h    = lane >> 5;

  // 1024 blocks: xcd=blk&7 hosts bh {4x..4x+3}; pair index = blk>>5
  const int blk = blockIdx.x;
  const int bh  = (blk & 7) * 4 + ((blk >> 3) & 3);
  const int sA  = blk >> 5;          // 0..31 (small set)
  const int sB  = 63 - sA;           // 32..63 (large set)
  const int t   = sB + 1;            // first A-unit in concatenated range [0,65)
  const int lo  = (65 * wave) >> 2;  // 0,16,32,48
  const int hi  = (65 * (wave + 1)) >> 2;   // 16,32,48,65

  const size_t fb = (size_t)bh * kFragBH;
  const u16* gk = Kf + fb + lane * 8;   // + k*2048 + dk*512
  const u16* gv = Vf + fb + lane * 8;   // + k*2048 + c*512

  float16v zf;
  #pragma unroll
  for (int i = 0; i < 16; ++i) zf[i] = 0.f;

  // current-set state
  int scur = (lo < t) ? sB : sA;
  int koff = (lo < t) ? 0 : t;

  short8 qf[4];
  {
    const u16* qp = Qf + fb + (size_t)(scur * 4) * 512 + lane * 8;
    #pragma unroll
    for (int dk = 0; dk < 4; ++dk) qf[dk] = *(const short8*)(qp + dk * 512);
  }

  float16v acc0 = zf, acc1 = zf;
  float lac = 0.f;

  auto dump = [&](int slot) {
    #pragma unroll
    for (int r = 0; r < 16; ++r) {
      const int row = (r & 3) + 8 * (r >> 2) + 4 * h;
      ldsP[slot][row][l31] = (u32)f2bf(acc0[r]) | ((u32)f2bf(acc1[r]) << 16);
    }
    const float lt = lac + __shfl_xor(lac, 32);
    if (lane < 32) ldsL[slot][lane] = lt;
  };

  for (int u = lo; u < hi; ++u) {
    if (u == t && u != lo) {          // B -> A transition (at most once)
      dump(wave);
      acc0 = zf; acc1 = zf; lac = 0.f;
      scur = sA; koff = t;
      const u16* qp = Qf + fb + (size_t)(sA * 4) * 512 + lane * 8;
      #pragma unroll
      for (int dk = 0; dk < 4; ++dk) qf[dk] = *(const short8*)(qp + dk * 512);
    }
    const int k = u - koff;

    const u16* kp = gk + (size_t)k * 2048;
    const u16* vp = gv + (size_t)k * 2048;
    short8 kf[4], vf[4];
    #pragma unroll
    for (int i = 0; i < 4; ++i) kf[i] = *(const short8*)(kp + i * 512);
    #pragma unroll
    for (int i = 0; i < 4; ++i) vf[i] = *(const short8*)(vp + i * 512);

    // S^T = K * Q^T (rows = keys, cols = q)
    __builtin_amdgcn_s_setprio(1);
    float16v sv = __builtin_amdgcn_mfma_f32_32x32x16_bf16(kf[0], qf[0], zf, 0, 0, 0);
    sv = __builtin_amdgcn_mfma_f32_32x32x16_bf16(kf[1], qf[1], sv, 0, 0, 0);
    sv = __builtin_amdgcn_mfma_f32_32x32x16_bf16(kf[2], qf[2], sv, 0, 0, 0);
    sv = __builtin_amdgcn_mfma_f32_32x32x16_bf16(kf[3], qf[3], sv, 0, 0, 0);
    __builtin_amdgcn_s_setprio(0);

    if (k == scur) {   // diagonal subtile of current set
      const int qg = scur * 32 + l31;
      #pragma unroll
      for (int r = 0; r < 16; ++r) {
        const int kg = k * 32 + (r & 3) + 8 * (r >> 2) + 4 * h;
        if (kg > qg) sv[r] = -1e30f;
      }
    }

    // p = exp2(s), pack (truncate) via v_perm
    u32 pk[8];
    #pragma unroll
    for (int g2 = 0; g2 < 4; ++g2) {
      const u32 u0 = __float_as_uint(__builtin_amdgcn_exp2f(sv[4 * g2 + 0]));
      const u32 u1 = __float_as_uint(__builtin_amdgcn_exp2f(sv[4 * g2 + 1]));
      const u32 u2 = __float_as_uint(__builtin_amdgcn_exp2f(sv[4 * g2 + 2]));
      const u32 u3 = __float_as_uint(__builtin_amdgcn_exp2f(sv[4 * g2 + 3]));
      pk[2 * g2]     = __builtin_amdgcn_perm(u1, u0, 0x07060302u);
      pk[2 * g2 + 1] = __builtin_amdgcn_perm(u3, u2, 0x07060302u);
    }

    // l partial: VALU sum of this lane's 16 bf16-truncated P values
    {
      float e[8];
      #pragma unroll
      for (int i = 0; i < 8; ++i)
        e[i] = __uint_as_float(pk[i] << 16)
             + __uint_as_float(pk[i] & 0xFFFF0000u);
      e[0] += e[1]; e[2] += e[3]; e[4] += e[5]; e[6] += e[7];
      e[0] += e[2]; e[4] += e[6];
      lac += e[0] + e[4];
    }

    // exchange partner half via permlane32_swap; PV MFMA
    {
      union { u32 u[4]; short8 s8; } pf;
      swap32(pk[0], pk[2], pf.u[0], pf.u[2]);
      swap32(pk[1], pk[3], pf.u[1], pf.u[3]);
      __builtin_amdgcn_s_setprio(1);
      acc0 = __builtin_amdgcn_mfma_f32_32x32x16_bf16(pf.s8, vf[0], acc0, 0, 0, 0);
      acc1 = __builtin_amdgcn_mfma_f32_32x32x16_bf16(pf.s8, vf[1], acc1, 0, 0, 0);
      __builtin_amdgcn_s_setprio(0);
    }
    {
      union { u32 u[4]; short8 s8; } pf;
      swap32(pk[4], pk[6], pf.u[0], pf.u[2]);
      swap32(pk[5], pk[7], pf.u[1], pf.u[3]);
      __builtin_amdgcn_s_setprio(1);
      acc0 = __builtin_amdgcn_mfma_f32_32x32x16_bf16(pf.s8, vf[2], acc0, 0, 0, 0);
      acc1 = __builtin_amdgcn_mfma_f32_32x32x16_bf16(pf.s8, vf[3], acc1, 0, 0, 0);
      __builtin_amdgcn_s_setprio(0);
    }
  }

  // final dump: transition wave's second partial -> slot 4, else own slot
  dump((lo < t && t < hi) ? 4 : wave);

  __syncthreads();

  // ---- in-block reduce: 2 sets x 32 q x 64 d; thread covers 8 packed u32 ----
  {
    const int setid = tid >> 7;          // 0 => B, 1 => A
    const int sOut  = setid ? sA : sB;
    // slot validity per set (chunk lows 0,16,32,48; t in [33,64])
    const bool v0 = setid ? (0  >= t) : (0  < t);
    const bool v1 = setid ? (16 >= t) : (16 < t);
    const bool v2 = setid ? (32 >= t) : (32 < t);
    const bool v3 = setid ? (48 >= t) : (48 < t);
    const bool v4 = (setid != 0) && (t != 48);   // transition partial is A

    const int q  = (tid & 127) >> 2;
    const int c0 = (tid & 3) * 8;

    float lsum = 0.f;
    if (v0) lsum += ldsL[0][q];
    if (v1) lsum += ldsL[1][q];
    if (v2) lsum += ldsL[2][q];
    if (v3) lsum += ldsL[3][q];
    if (v4) lsum += ldsL[4][q];
    const float inv = 1.f / lsum;

    float* op = O + ((size_t)bh * kS + sOut * 32 + q) * kD;
    #pragma unroll
    for (int i = 0; i < 8; ++i) {
      const int c = c0 + i;
      float lov = 0.f, hiv = 0.f;
      if (v0) { const u32 p = ldsP[0][q][c]; lov += __uint_as_float(p << 16); hiv += __uint_as_float(p & 0xFFFF0000u); }
      if (v1) { const u32 p = ldsP[1][q][c]; lov += __uint_as_float(p << 16); hiv += __uint_as_float(p & 0xFFFF0000u); }
      if (v2) { const u32 p = ldsP[2][q][c]; lov += __uint_as_float(p << 16); hiv += __uint_as_float(p & 0xFFFF0000u); }
      if (v3) { const u32 p = ldsP[3][q][c]; lov += __uint_as_float(p << 16); hiv += __uint_as_float(p & 0xFFFF0000u); }
      if (v4) { const u32 p = ldsP[4][q][c]; lov += __uint_as_float(p << 16); hiv += __uint_as_float(p & 0xFFFF0000u); }
      op[c]      = lov * inv;
      op[c + 32] = hiv * inv;
    }
  }
}

extern "C" void kernel_launch(void* const* d_in, const int* in_sizes, int n_in,
                              void* d_out, int out_size, void* d_ws, size_t ws_size,
                              hipStream_t stream) {
  const float* Q = (const float*)d_in[0];
  const float* K = (const float*)d_in[1];
  const float* V = (const float*)d_in[2];
  float* O = (float*)d_out;

  const size_t nKV = (size_t)kBH * kS * kD;      // 4.19M elems
  u16* Qf = (u16*)d_ws;                          // 8.39 MB
  u16* Kf = Qf + nKV;                            // 8.39 MB
  u16* Vf = Kf + nKV;                            // 8.39 MB

  dim3 gprep(kS / 64, kBH);
  prep_kernel<<<gprep, 256, 0, stream>>>(Q, K, V, Qf, Kf, Vf);
  fattn_kernel<<<1024, 256, 0, stream>>>(Qf, Kf, Vf, O);
}